// Round 1
// baseline (218.171 us; speedup 1.0000x reference)
//
#include <hip/hip_runtime.h>
#include <hip/hip_bf16.h>
#include <stdint.h>

#define Bsz 4096
#define Dn  512
#define Kn  128
#define Pn  16
#define An  32
#define TB  16

typedef __attribute__((ext_vector_type(4))) float  floatx4;
typedef __attribute__((ext_vector_type(8))) short  shortx8;

__device__ __forceinline__ unsigned short f2bf(float x) {
    union { float f; uint32_t u; } v; v.f = x;
    uint32_t u = v.u;
    uint32_t r = (u + 0x7FFFu + ((u >> 16) & 1u)) >> 16;
    return (unsigned short)r;
}

// ---------------- K1: mu = alpha @ W (bf16 row-major + bf16 transposed) + ||mu_k||^2 ----------------
__global__ __launch_bounds__(256) void k_mu(const float* __restrict__ alpha,
                                            const float* __restrict__ W,
                                            unsigned short* __restrict__ mu_bf,
                                            unsigned short* __restrict__ mu_t,
                                            float* __restrict__ munorm,
                                            float* __restrict__ out) {
    __shared__ float al[An];
    __shared__ float red[4];
    int k = blockIdx.x, t = threadIdx.x;
    if (k == 0 && t == 0) *out = 0.f;        // replaces the memset dispatch
    if (t < An) al[t] = alpha[k * An + t];
    __syncthreads();
    int d0 = t, d1 = t + 256;
    float a0 = 0.f, a1 = 0.f;
#pragma unroll
    for (int a = 0; a < An; ++a) {
        float av = al[a];
        a0 = fmaf(av, W[a * Dn + d0], a0);
        a1 = fmaf(av, W[a * Dn + d1], a1);
    }
    unsigned short h0 = f2bf(a0), h1 = f2bf(a1);
    mu_bf[k * Dn + d0] = h0;  mu_bf[k * Dn + d1] = h1;
    // transposed copy: mu_t[d][k] -> contiguous-in-k shortx8 B-fragments for w@mu
    mu_t[d0 * Kn + k] = h0;   mu_t[d1 * Kn + k] = h1;
    float nrm = a0 * a0 + a1 * a1;
#pragma unroll
    for (int msk = 1; msk < 64; msk <<= 1) nrm += __shfl_xor(nrm, msk);
    if ((t & 63) == 0) red[t >> 6] = nrm;
    __syncthreads();
    if (t == 0) munorm[k] = red[0] + red[1] + red[2] + red[3];
}

// ---------------- K3: fused S/softmax/wGw + streaming probe contraction ----------------
// wGw = ||w @ mu||^2 computed in-block from mu_t (k_gram eliminated).
// 1 barrier per probe: LDS vt[2] + part[2] double-buffered; prefetch issued
// AFTER the barrier so __syncthreads' vmcnt(0) drain never kills the overlap.
__global__ __launch_bounds__(512, 4) void k_main(
    const float* __restrict__ thetas,
    const int* __restrict__ v_int,
    const unsigned short* __restrict__ mu_bf,
    const float* __restrict__ munorm,
    const unsigned short* __restrict__ mu_t,
    const int* __restrict__ Np,
    float* __restrict__ out)
{
    __shared__ short vt[2][TB][520];
    __shared__ float S_l[TB][132];
    __shared__ float w_l[TB][132];
    __shared__ short wbf[TB][136];
    __shared__ float part[2][8][TB][2];
    __shared__ float thn[TB];
    __shared__ float SwS[TB];

    const int tid = threadIdx.x;
    const int lane = tid & 63;
    const int wv = tid >> 6;
    const int m = lane & 15;
    const int q = lane >> 4;

    const int tileb = blockIdx.x >> 1;
    const int phalf = blockIdx.x & 1;
    const int b0 = tileb * TB;
    const int p0 = phalf * 8;

    const float Nf = (float)(*Np);
    const float temper = Nf / (Nf + 1.0f);

    const int kcol = wv * 16 + m;
    shortx8 mufrag[16];
    {
        const unsigned short* mb = mu_bf + (size_t)kcol * Dn + q * 8;
#pragma unroll
        for (int dc = 0; dc < 16; ++dc)
            mufrag[dc] = *(const shortx8*)(mb + dc * 32);
    }

    const int r = tid >> 5;
    const int c0 = (tid & 31) * 16;
    const size_t PB = (size_t)Bsz * Dn;
    const int* vrow = v_int + (size_t)(b0 + r) * Dn + c0;

    int4 buf[4];
    {   // prefetch probe p0 (lands during prologue; consumed at loop p=0)
        const int4* g = (const int4*)(vrow + (size_t)p0 * PB);
#pragma unroll
        for (int j = 0; j < 4; ++j) buf[j] = g[j];
    }
    {   // stage theta -> vt[0] (bf16), ||theta||^2 fp32
        const float4* tg = (const float4*)(thetas + (size_t)(b0 + r) * Dn + c0);
        float tn = 0.f;
#pragma unroll
        for (int j = 0; j < 4; ++j) {
            float4 f = tg[j];
            tn += f.x * f.x + f.y * f.y + f.z * f.z + f.w * f.w;
            short4 h;
            h.x = (short)f2bf(f.x); h.y = (short)f2bf(f.y);
            h.z = (short)f2bf(f.z); h.w = (short)f2bf(f.w);
            *(short4*)&vt[0][r][c0 + j * 4] = h;
        }
#pragma unroll
        for (int msk = 1; msk < 32; msk <<= 1) tn += __shfl_xor(tn, msk);
        if ((tid & 31) == 0) thn[r] = tn;
    }
    __syncthreads();

    // ---- S = theta @ mu^T ----
    {
        floatx4 acc = {0.f, 0.f, 0.f, 0.f};
#pragma unroll
        for (int dc = 0; dc < 16; ++dc) {
            shortx8 a = *(const shortx8*)&vt[0][m][dc * 32 + q * 8];
            acc = __builtin_amdgcn_mfma_f32_16x16x32_bf16(a, mufrag[dc], acc, 0, 0, 0);
        }
#pragma unroll
        for (int i = 0; i < 4; ++i) S_l[q * 4 + i][kcol] = acc[i];
    }
    __syncthreads();

    // ---- softmax over k (32 threads per b-row) ----
    {
        const int b = tid >> 5, s = tid & 31;
        float l[4];
        float mx = -3.4e38f;
        float tnb = thn[b];
#pragma unroll
        for (int j = 0; j < 4; ++j) {
            int k = s + 32 * j;
            l[j] = -0.5f * (tnb - 2.f * S_l[b][k] + munorm[k]);
            mx = fmaxf(mx, l[j]);
        }
#pragma unroll
        for (int msk = 1; msk < 32; msk <<= 1) mx = fmaxf(mx, __shfl_xor(mx, msk));
        float se = 0.f, ses = 0.f;
        float e[4];
#pragma unroll
        for (int j = 0; j < 4; ++j) {
            int k = s + 32 * j;
            e[j] = __expf(l[j] - mx);
            se += e[j];
            ses += e[j] * S_l[b][k];
        }
#pragma unroll
        for (int msk = 1; msk < 32; msk <<= 1) { se += __shfl_xor(se, msk); ses += __shfl_xor(ses, msk); }
        float inv = 1.f / se;
#pragma unroll
        for (int j = 0; j < 4; ++j) {
            int k = s + 32 * j;
            float wvv = e[j] * inv;
            w_l[b][k] = wvv;
            wbf[b][k] = (short)f2bf(wvv);
        }
        if (s == 0) SwS[b] = ses * inv;
    }
    __syncthreads();

    // ---- wGw = ||y||^2 with y = w @ mu  (replaces Gram kernel + G-read) ----
    // wave wv owns d-columns [wv*64, wv*64+64); per ct a 16x16 y-tile,
    // B-frags are contiguous shortx8 from mu_t[d][k] (L2-resident, 128 KB).
    {
        float sg[4] = {0.f, 0.f, 0.f, 0.f};
#pragma unroll
        for (int ct = 0; ct < 4; ++ct) {
            const unsigned short* mt = mu_t + (size_t)(wv * 64 + ct * 16 + m) * Kn + q * 8;
            floatx4 acc = {0.f, 0.f, 0.f, 0.f};
#pragma unroll
            for (int kc = 0; kc < 4; ++kc) {
                shortx8 a = *(const shortx8*)&wbf[m][kc * 32 + q * 8];
                shortx8 bfr = *(const shortx8*)(mt + kc * 32);
                acc = __builtin_amdgcn_mfma_f32_16x16x32_bf16(a, bfr, acc, 0, 0, 0);
            }
#pragma unroll
            for (int i = 0; i < 4; ++i) sg[i] += acc[i] * acc[i];
        }
#pragma unroll
        for (int msk = 1; msk < 16; msk <<= 1) {
#pragma unroll
            for (int i = 0; i < 4; ++i) sg[i] += __shfl_xor(sg[i], msk);
        }
        if (m == 0) {
#pragma unroll
            for (int i = 0; i < 4; ++i) part[0][wv][q * 4 + i][0] = sg[i];
        }
    }
    __syncthreads();

    float lossA = 0.f, tracc = 0.f;
    if (tid < TB) {
        float wGw = 0.f;
#pragma unroll
        for (int w8 = 0; w8 < 8; ++w8) wGw += part[0][w8][tid][0];
        if (phalf == 0)
            lossA = 0.5f * temper * temper * (wGw - 2.f * SwS[tid] + thn[tid])
                    - temper * (float)Dn;
    }
    // readers above finish before probe-0's part[0] writes (those follow barrier p=0)

    // ---- probe loop: 1 barrier per probe ----
#pragma unroll
    for (int p = 0; p < 8; ++p) {
        // convert current buf -> vt[p&1]  (safe: reads of this buffer from
        // probe p-2 completed before barrier p-1)
        // bf16(2v-1): v=1 -> 0x3F80, v=0 -> 0xBF80 == 0xBF80 ^ (v<<15)
#pragma unroll
        for (int j = 0; j < 4; ++j) {
            int4 w4 = buf[j];
            uint32_t lo = 0xBF80BF80u ^ ((uint32_t)w4.x << 15) ^ ((uint32_t)w4.y << 31);
            uint32_t hi = 0xBF80BF80u ^ ((uint32_t)w4.z << 15) ^ ((uint32_t)w4.w << 31);
            uint2 pk; pk.x = lo; pk.y = hi;
            *(uint2*)&vt[p & 1][r][c0 + j * 4] = pk;
        }
        __syncthreads();
        // prefetch AFTER the barrier: never drained by syncthreads' vmcnt(0);
        // lands during MFMA phase, consumed at next iteration's convert
        if (p < 7) {
            const int4* g = (const int4*)(vrow + (size_t)(p0 + p + 1) * PB);
#pragma unroll
            for (int j = 0; j < 4; ++j) buf[j] = g[j];
        }
        if (p > 0 && tid < TB) {
            float S1 = 0.f, S2 = 0.f;
#pragma unroll
            for (int w8 = 0; w8 < 8; ++w8) {
                S1 += part[(p - 1) & 1][w8][tid][0];
                S2 += part[(p - 1) & 1][w8][tid][1];
            }
            tracc += S1 - S2 * S2;
        }
        floatx4 acc = {0.f, 0.f, 0.f, 0.f};
#pragma unroll
        for (int dc = 0; dc < 16; ++dc) {
            shortx8 a = *(const shortx8*)&vt[p & 1][m][dc * 32 + q * 8];
            acc = __builtin_amdgcn_mfma_f32_16x16x32_bf16(a, mufrag[dc], acc, 0, 0, 0);
        }
        float s1[4], s2[4];
#pragma unroll
        for (int i = 0; i < 4; ++i) {
            float T = acc[i];
            float wt = w_l[q * 4 + i][kcol];
            s1[i] = wt * T * T;
            s2[i] = wt * T;
        }
#pragma unroll
        for (int msk = 1; msk < 16; msk <<= 1) {
#pragma unroll
            for (int i = 0; i < 4; ++i) {
                s1[i] += __shfl_xor(s1[i], msk);
                s2[i] += __shfl_xor(s2[i], msk);
            }
        }
        if (m == 0) {
#pragma unroll
            for (int i = 0; i < 4; ++i) {
                part[p & 1][wv][q * 4 + i][0] = s1[i];
                part[p & 1][wv][q * 4 + i][1] = s2[i];
            }
        }
        // no trailing barrier: next iteration's barrier orders part/vt reuse
    }
    __syncthreads();
    if (tid < TB) {
        float S1 = 0.f, S2 = 0.f;
#pragma unroll
        for (int w8 = 0; w8 < 8; ++w8) {
            S1 += part[1][w8][tid][0];
            S2 += part[1][w8][tid][1];
        }
        tracc += S1 - S2 * S2;
        float res = temper * tracc * (1.0f / (float)Pn) + lossA;
#pragma unroll
        for (int msk = 1; msk < 16; msk <<= 1) res += __shfl_xor(res, msk);
        if (tid == 0) atomicAdd(out, res * (1.0f / (float)Bsz));
    }
}

extern "C" void kernel_launch(void* const* d_in, const int* in_sizes, int n_in,
                              void* d_out, int out_size, void* d_ws, size_t ws_size,
                              hipStream_t stream) {
    const float* thetas = (const float*)d_in[0];
    const float* alpha  = (const float*)d_in[1];
    const float* W      = (const float*)d_in[2];
    const int*   v_int  = (const int*)d_in[3];
    const int*   Np     = (const int*)d_in[4];

    char* ws = (char*)d_ws;
    unsigned short* mu_bf  = (unsigned short*)ws;                    // 128 KB
    float*          munorm = (float*)(ws + 131072);                  // 512 B
    unsigned short* mu_t   = (unsigned short*)(ws + 131072 + 1024);  // 128 KB transposed

    float* out = (float*)d_out;
    k_mu  <<<dim3(Kn),  dim3(256), 0, stream>>>(alpha, W, mu_bf, mu_t, munorm, out);
    k_main<<<dim3(512), dim3(512), 0, stream>>>(thetas, v_int, mu_bf, munorm, mu_t, Np, out);
}